// Round 1
// baseline (8677.673 us; speedup 1.0000x reference)
//
#include <hip/hip_runtime.h>

typedef _Float16 h8 __attribute__((ext_vector_type(8)));
typedef _Float16 h4 __attribute__((ext_vector_type(4)));
typedef float    f4 __attribute__((ext_vector_type(4)));
typedef unsigned u32x4 __attribute__((ext_vector_type(4)));

// ---------------- workspace layout (bytes) ----------------
// hbuf32 : 2*8*8*512 fp32 = 262,144  [parity][ig 8][row 8][unit 512]
//          each dword: fp32 h with 10-bit step tag in mantissa LSBs
static const unsigned long long OFF_HBUF  = 0ull;
static const unsigned long long WS_NEEDED = 262144ull;

__device__ __forceinline__ float sigm(float x)   { return 1.0f / (1.0f + __expf(-x)); }
__device__ __forceinline__ float tanh_a(float x) { return 2.0f / (1.0f + __expf(-2.0f * x)) - 1.0f; }

// ---------------- k_init: fill h buffer with tag=1023, value~0 ----------------
__global__ __launch_bounds__(256) void k_init(unsigned* hbuf)
{
    const int idx = blockIdx.x * 256 + threadIdx.x;
    if (idx < 65536) hbuf[idx] = 0x000003FFu;
}

// R8: exchange path redesign.
// - Teams (same ig = bx&7) are XCD-affine under bx%8 dispatch -> publish with
//   PLAIN stores (shared L2) + sc0sc1 mirror (MALL, fallback only); spin with
//   sc0 loads (L1 bypass, L2 hit ~200cy instead of MALL ~900cy). After 16
//   failed probes a lane escalates to sc0sc1 loads, so correctness does NOT
//   depend on the XCD mapping -- only the fast path does.
// - Per-thread spin (no ballot/consensus/barriers in the retry loop).
// - Double-buffered ldsH/ldsX -> exactly ONE __syncthreads per step.
// - Staging is 4x dwordx4 loads + 8B LDS writes with (row+kc)&7 block rotation
//   (old layout: 64 lanes -> 4 banks, 4.2e7 conflict cycles/dispatch).
// First probe issues BEFORE the x@U MFMA phase so L2 latency hides under MFMA
// issue. waitcnt lives in separate asm; sched_barrier(0) pins the tag check
// after it (rule 18: early-clobber alone does not stop the hoist).

#define HPROBE(FLAGS) \
    asm volatile("global_load_dwordx4 %0, %4, off " FLAGS "\n\t"              \
                 "global_load_dwordx4 %1, %4, off offset:2048 " FLAGS "\n\t"  \
                 "global_load_dwordx4 %2, %5, off " FLAGS "\n\t"              \
                 "global_load_dwordx4 %3, %5, off offset:2048 " FLAGS         \
                 : "=&v"(qa), "=&v"(qb), "=&v"(qc), "=&v"(qd)                 \
                 : "v"(hb0), "v"(hb1)                                         \
                 : "memory")

#define HWAIT() do {                                                          \
    asm volatile("s_waitcnt vmcnt(0)" ::: "memory");                          \
    __builtin_amdgcn_sched_barrier(0);                                        \
} while (0)

#define REPACK_ROW(Q, J) do {                                                 \
    h4 p_;                                                                    \
    p_[0] = (_Float16)__uint_as_float(Q[0] & 0xFFFFFC00u);                    \
    p_[1] = (_Float16)__uint_as_float(Q[1] & 0xFFFFFC00u);                    \
    p_[2] = (_Float16)__uint_as_float(Q[2] & 0xFFFFFC00u);                    \
    p_[3] = (_Float16)__uint_as_float(Q[3] & 0xFFFFFC00u);                    \
    *(h4*)&ldsH[pb][(size_t)((hkc * 32 + hhh * 8 + (((hr0 + (J)) + hkc) & 7)) * 8 + hjj)] = p_; \
} while (0)

#define XSTAGE_ROW(PX, V, ROW) do {                                           \
    h4 p_;                                                                    \
    p_[0] = (_Float16)V[0]; p_[1] = (_Float16)V[1];                           \
    p_[2] = (_Float16)V[2]; p_[3] = (_Float16)V[3];                           \
    *(h4*)&ldsX[PX][(size_t)((xkc * 32 + xhh * 8 + (((ROW) + xkc) & 7)) * 8 + xjj)] = p_; \
} while (0)

__global__ __launch_bounds__(256, 1) void k_rec(
    const float* __restrict__ x,
    const float* __restrict__ Ui, const float* __restrict__ Vi, const float* __restrict__ bi,
    const float* __restrict__ Uf, const float* __restrict__ Vf, const float* __restrict__ bf,
    const float* __restrict__ Uh, const float* __restrict__ Vh, const float* __restrict__ bh,
    const float* __restrict__ Uo, const float* __restrict__ Vo, const float* __restrict__ bo,
    unsigned* hbuf)
{
    const int bx = blockIdx.x;
    const int ig = bx & 7;      // bx&7 -> XCD-affine team (fast path only)
    const int jg = bx >> 3;
    const int tid = threadIdx.x;
    const int w = tid >> 6, l = tid & 63;
    const int lo = l & 15, hi = l >> 4;
    const int r8 = lo & 7;                           // batch row within group
    const int unit = jg * 64 + w * 16 + lo;          // hidden unit [0,512)

    // double-buffered fragment stores: [par][kc][g 32][8 fp16]
    __shared__ __align__(16) _Float16 ldsH[2][16 * 32 * 8];   // 16 KB
    __shared__ __align__(16) _Float16 ldsX[2][8 * 32 * 8];    //  8 KB

    const float* Ug[4] = {Ui, Uf, Uh, Uo};
    const float* Vg[4] = {Vi, Vf, Vh, Vo};
    const float* bg[4] = {bi, bf, bh, bo};

    // ---- one-time fragment preload (fp32 -> fp16 cvt) ----
    h8 vfrag[4][16];   // V: K=512 -> 16 k-chunks
    h8 ufrag[4][8];    // U: K=256 ->  8 k-chunks
    float bias[4];
#pragma unroll
    for (int g = 0; g < 4; ++g) {
        bias[g] = bg[g][unit];
#pragma unroll
        for (int kc = 0; kc < 16; ++kc) {
            h8 v;
#pragma unroll
            for (int jj = 0; jj < 8; ++jj)
                v[jj] = (_Float16)Vg[g][(size_t)(kc * 32 + hi * 8 + jj) * 512 + unit];
            vfrag[g][kc] = v;
        }
#pragma unroll
        for (int kc = 0; kc < 8; ++kc) {
            h8 u;
#pragma unroll
            for (int jj = 0; jj < 8; ++jj)
                u[jj] = (_Float16)Ug[g][(size_t)(kc * 32 + hi * 8 + jj) * 512 + unit];
            ufrag[g][kc] = u;
        }
    }

    // ---- staging maps ----
    // h: thread covers units hu0..hu0+3 for rows hr0..hr0+3 (4 x dwordx4)
    const int hu0 = 4 * (tid & 127), hr0 = 4 * (tid >> 7);
    const int hkc = hu0 >> 5, hhh = (hu0 >> 3) & 3, hjj = hu0 & 7;
    // x: thread covers i-units i0..i0+3 for rows xr0, xr0+1 (2 x dwordx4)
    const int i0 = 4 * (tid & 63), xr0 = 2 * (tid >> 6);
    const int xkc = i0 >> 5, xhh = (i0 >> 3) & 3, xjj = i0 & 7;
    const float* xrb = x + (size_t)(ig * 8 + xr0) * 262144 + i0;

    f4 cst = {0.f, 0.f, 0.f, 0.f};   // cell state, C-layout rows hi*4+d
    f4 xq0, xq1;                     // prefetched x_{t+1} rows xr0, xr0+1

    // ---- prologue: stage x_0 into ldsX[0], prefetch x_1 ----
    {
        f4 a0 = *(const f4*)(xrb);
        f4 a1 = *(const f4*)(xrb + 262144);
        XSTAGE_ROW(0, a0, xr0);
        XSTAGE_ROW(0, a1, xr0 + 1);
        xq0 = *(const f4*)(xrb + 256);
        xq1 = *(const f4*)(xrb + 262144 + 256);
        __syncthreads();
    }

    for (int t = 0; t < 1024; ++t) {
        const int pb = t & 1;                    // lds read parity + publish parity
        const int pr = (t + 1) & 1;              // hbuf slab holding h_{t-1}
        const unsigned etag = (unsigned)((t + 1023) & 1023);

        const unsigned* hb0 = hbuf + (size_t)(pr * 8 + ig) * 4096 + (size_t)hr0 * 512 + hu0;
        const unsigned* hb1 = hb0 + 1024;        // rows hr0+2, hr0+3

        // ---- issue first h probe (L2-scope), hides under phase A ----
        u32x4 qa, qb, qc, qd;
        HPROBE("sc0");

        // ---- phase A: gate-init = bias + x_t @ U (from ldsX[pb]) ----
        f4 acc[4];
#pragma unroll
        for (int g = 0; g < 4; ++g) {
            f4 a; a[0] = bias[g]; a[1] = bias[g]; a[2] = bias[g]; a[3] = bias[g];
            acc[g] = a;
        }
#pragma unroll
        for (int kc = 0; kc < 8; ++kc) {
            const h8 xa = *(const h8*)&ldsX[pb][(size_t)((kc * 32 + hi * 8 + ((r8 + kc) & 7)) * 8)];
            acc[0] = __builtin_amdgcn_mfma_f32_16x16x32_f16(xa, ufrag[0][kc], acc[0], 0, 0, 0);
            acc[1] = __builtin_amdgcn_mfma_f32_16x16x32_f16(xa, ufrag[1][kc], acc[1], 0, 0, 0);
            acc[2] = __builtin_amdgcn_mfma_f32_16x16x32_f16(xa, ufrag[2][kc], acc[2], 0, 0, 0);
            acc[3] = __builtin_amdgcn_mfma_f32_16x16x32_f16(xa, ufrag[3][kc], acc[3], 0, 0, 0);
        }

        // ---- per-thread tagged spin (no block consensus) ----
        HWAIT();
        {
            int tries = 0;
            for (;;) {
                const unsigned m =
                    (qa[0]^etag)|(qa[1]^etag)|(qa[2]^etag)|(qa[3]^etag)|
                    (qb[0]^etag)|(qb[1]^etag)|(qb[2]^etag)|(qb[3]^etag)|
                    (qc[0]^etag)|(qc[1]^etag)|(qc[2]^etag)|(qc[3]^etag)|
                    (qd[0]^etag)|(qd[1]^etag)|(qd[2]^etag)|(qd[3]^etag);
                if (!(m & 1023u)) break;
                ++tries;
                if (tries > 32768) break;        // safety valve: fails absmax, not hangs
                if (tries < 16) { HPROBE("sc0"); }
                else            { HPROBE("sc0 sc1"); }   // mapping-independent fallback
                HWAIT();
            }
        }

        // ---- stage h -> fp16 -> ldsH[pb] (swizzled 8B writes) ----
        REPACK_ROW(qa, 0); REPACK_ROW(qb, 1); REPACK_ROW(qc, 2); REPACK_ROW(qd, 3);

        // ---- stage x_{t+1} -> ldsX[pr]; issue x_{t+2} loads ----
        XSTAGE_ROW(pr, xq0, xr0);
        XSTAGE_ROW(pr, xq1, xr0 + 1);
        {
            const int tn = (t + 2 < 1024) ? (t + 2) : 1023;
            const float* xb = xrb + (size_t)tn * 256;
            xq0 = *(const f4*)(xb);
            xq1 = *(const f4*)(xb + 262144);
        }

        __syncthreads();   // the ONLY barrier per step

        // ---- phase C: h_{t-1} @ V from ldsH[pb] (b128 reads, conflict-free) ----
#pragma unroll
        for (int kc = 0; kc < 16; ++kc) {
            const h8 a = *(const h8*)&ldsH[pb][(size_t)((kc * 32 + hi * 8 + ((r8 + kc) & 7)) * 8)];
            acc[0] = __builtin_amdgcn_mfma_f32_16x16x32_f16(a, vfrag[0][kc], acc[0], 0, 0, 0);
            acc[1] = __builtin_amdgcn_mfma_f32_16x16x32_f16(a, vfrag[1][kc], acc[1], 0, 0, 0);
            acc[2] = __builtin_amdgcn_mfma_f32_16x16x32_f16(a, vfrag[2][kc], acc[2], 0, 0, 0);
            acc[3] = __builtin_amdgcn_mfma_f32_16x16x32_f16(a, vfrag[3][kc], acc[3], 0, 0, 0);
        }

        // ---- elementwise + tagged publish: plain (L2 fast path) + sc0sc1 mirror ----
        const unsigned ptag = (unsigned)(t & 1023);
        unsigned pub[4];
#pragma unroll
        for (int d = 0; d < 4; ++d) {
            const float iv = sigm(acc[0][d]);
            const float fv = sigm(acc[1][d]);
            const float gv = tanh_a(acc[2][d]);
            const float ov = sigm(acc[3][d]);
            const float c = fv * cst[d] + iv * gv;
            cst[d] = c;
            const float hv = ov * tanh_a(c);
            pub[d] = (__float_as_uint(hv) & 0xFFFFFC00u) | ptag;
        }
        if (hi < 2) {
            unsigned* hw = hbuf + (size_t)((pb * 8 + ig) * 8 + hi * 4) * 512 + unit;
            asm volatile(
                "global_store_dword %4, %0, off\n\t"
                "global_store_dword %4, %0, off sc0 sc1\n\t"
                "global_store_dword %4, %1, off offset:2048\n\t"
                "global_store_dword %4, %1, off offset:2048 sc0 sc1\n\t"
                "global_store_dword %5, %2, off\n\t"
                "global_store_dword %5, %2, off sc0 sc1\n\t"
                "global_store_dword %5, %3, off offset:2048\n\t"
                "global_store_dword %5, %3, off offset:2048 sc0 sc1"
                :: "v"(pub[0]), "v"(pub[1]), "v"(pub[2]), "v"(pub[3]),
                   "v"(hw), "v"(hw + 1024)
                : "memory");
        }
    }
}

// ---------------- k_fc: out[b] = h_last[b,:] . fc_w + fc_b ----------------
__global__ __launch_bounds__(64) void k_fc(
    const unsigned* __restrict__ hbuf, const float* __restrict__ fcw,
    const float* __restrict__ fcb, float* __restrict__ out)
{
    const int b = blockIdx.x, l = threadIdx.x;
    // h_1023 lives at parity 1; ig = b>>3, row = b&7; mask the tag bits
    const unsigned* h = hbuf + (size_t)((8 + (b >> 3)) * 8 + (b & 7)) * 512;
    float s = 0.f;
#pragma unroll
    for (int k = 0; k < 8; ++k) {
        const float hv = __uint_as_float(h[l + k * 64] & 0xFFFFFC00u);
        s += hv * fcw[l + k * 64];
    }
    for (int off = 32; off > 0; off >>= 1) s += __shfl_down(s, off, 64);
    if (l == 0) out[b] = s + fcb[0];
}

__global__ __launch_bounds__(64) void k_sentinel(float* out)
{
    out[threadIdx.x] = -777777.0f;   // signature: ws_size too small
}

extern "C" void kernel_launch(void* const* d_in, const int* in_sizes, int n_in,
                              void* d_out, int out_size, void* d_ws, size_t ws_size,
                              hipStream_t stream)
{
    const float* x   = (const float*)d_in[0];
    const float* Ui  = (const float*)d_in[1];
    const float* Vi  = (const float*)d_in[2];
    const float* bi  = (const float*)d_in[3];
    const float* Uf  = (const float*)d_in[4];
    const float* Vf  = (const float*)d_in[5];
    const float* bf  = (const float*)d_in[6];
    const float* Uh  = (const float*)d_in[7];
    const float* Vh  = (const float*)d_in[8];
    const float* bh  = (const float*)d_in[9];
    const float* Uo  = (const float*)d_in[10];
    const float* Vo  = (const float*)d_in[11];
    const float* bo  = (const float*)d_in[12];
    const float* fcw = (const float*)d_in[13];
    const float* fcb = (const float*)d_in[14];
    float* out = (float*)d_out;

    if (ws_size < WS_NEEDED) {
        k_sentinel<<<1, 64, 0, stream>>>(out);
        return;
    }

    unsigned* hbuf = (unsigned*)((char*)d_ws + OFF_HBUF);

    k_init<<<256, 256, 0, stream>>>(hbuf);
    k_rec <<<64,  256, 0, stream>>>(x, Ui, Vi, bi, Uf, Vf, bf, Uh, Vh, bh,
                                    Uo, Vo, bo, hbuf);
    k_fc  <<<64,   64, 0, stream>>>(hbuf, fcw, fcb, out);
}

// Round 2
// 3377.620 us; speedup vs baseline: 2.5692x; 2.5692x over previous
//
#include <hip/hip_runtime.h>

typedef _Float16 h8 __attribute__((ext_vector_type(8)));
typedef float    f4 __attribute__((ext_vector_type(4)));
typedef unsigned u4 __attribute__((ext_vector_type(4)));

// ---------------- workspace layout (bytes) ----------------
// hbuf32 : 2*8*8*512 fp32 = 262,144  [parity][ig 8][row 8][unit 512]
//          each dword: fp32 h with 10-bit step tag in mantissa LSBs
static const unsigned long long WS_NEEDED = 262144ull;

__device__ __forceinline__ float sigm(float x)   { return 1.0f / (1.0f + __expf(-x)); }
__device__ __forceinline__ float tanh_a(float x) { return 2.0f / (1.0f + __expf(-2.0f * x)) - 1.0f; }

// ---------------- k_init: fill h buffer with tag=1023, value~0 ----------------
__global__ __launch_bounds__(256) void k_init(unsigned* hbuf)
{
    const int idx = blockIdx.x * 256 + threadIdx.x;
    if (idx < 65536) hbuf[idx] = 0x000003FFu;
}

// R9: revert to R7's proven agent-scope (sc0 sc1) protocol; R8's L2-scope
// fast path was structurally stale (consumer L2 caches the old line; nothing
// invalidates it -> 16 wasted probes/step). Changes vs R7, all keeping
// agent scope:
//  1. per-thread tag spin (no ballot/consensus barriers in retry path)
//  2. h probes issued BEFORE x@U MFMA; counted vmcnt(2) lets half-2 loads
//     stay in flight across the first V-MFMA half (raw s_barrier, not
//     __syncthreads, so the pipeline isn't drained at the barrier)
//  3. XOR-swizzled LDS staging (both write and read sides): one b128 write
//     per thread per half, evenly spread over 32 banks (R7: 16-way conflict)
//  4. x staged as 2x dwordx4 + 1x b128 (was 8 scalar loads)
// All step-loop VMEM is inline asm -> deterministic vmcnt counts. Every
// s_waitcnt is followed by sched_barrier(0) (rule 18).

#define VWAIT2() do { asm volatile("s_waitcnt vmcnt(2)" ::: "memory"); \
                      __builtin_amdgcn_sched_barrier(0); } while (0)
#define VWAIT0() do { asm volatile("s_waitcnt vmcnt(0)" ::: "memory"); \
                      __builtin_amdgcn_sched_barrier(0); } while (0)
#define LBAR()   do { asm volatile("s_waitcnt lgkmcnt(0)" ::: "memory"); \
                      __builtin_amdgcn_s_barrier(); \
                      __builtin_amdgcn_sched_barrier(0); } while (0)

__device__ __forceinline__ h8 pack8h(u4 a, u4 b)
{
    h8 p;
    p[0] = (_Float16)__uint_as_float(a[0] & 0xFFFFFC00u);
    p[1] = (_Float16)__uint_as_float(a[1] & 0xFFFFFC00u);
    p[2] = (_Float16)__uint_as_float(a[2] & 0xFFFFFC00u);
    p[3] = (_Float16)__uint_as_float(a[3] & 0xFFFFFC00u);
    p[4] = (_Float16)__uint_as_float(b[0] & 0xFFFFFC00u);
    p[5] = (_Float16)__uint_as_float(b[1] & 0xFFFFFC00u);
    p[6] = (_Float16)__uint_as_float(b[2] & 0xFFFFFC00u);
    p[7] = (_Float16)__uint_as_float(b[3] & 0xFFFFFC00u);
    return p;
}
__device__ __forceinline__ h8 pack8f(f4 a, f4 b)
{
    h8 p;
    p[0] = (_Float16)a[0]; p[1] = (_Float16)a[1];
    p[2] = (_Float16)a[2]; p[3] = (_Float16)a[3];
    p[4] = (_Float16)b[0]; p[5] = (_Float16)b[1];
    p[6] = (_Float16)b[2]; p[7] = (_Float16)b[3];
    return p;
}

__global__ __launch_bounds__(256, 1) void k_rec(
    const float* __restrict__ x,
    const float* __restrict__ Ui, const float* __restrict__ Vi, const float* __restrict__ bi,
    const float* __restrict__ Uf, const float* __restrict__ Vf, const float* __restrict__ bf,
    const float* __restrict__ Uh, const float* __restrict__ Vh, const float* __restrict__ bh,
    const float* __restrict__ Uo, const float* __restrict__ Vo, const float* __restrict__ bo,
    unsigned* hbuf)
{
    const int bx = blockIdx.x;
    const int ig = bx & 7;
    const int jg = bx >> 3;
    const int tid = threadIdx.x;
    const int w = tid >> 6, l = tid & 63;
    const int lo = l & 15, hi = l >> 4;
    const int r8 = lo & 7;
    const int unit = jg * 64 + w * 16 + lo;

    // single-buffered ldsH (barrier analysis: step-t writes of a region only
    // happen after all step-(t-1) reads of it passed a barrier); double ldsX
    __shared__ __align__(16) _Float16 ldsH[16 * 32 * 8];      // 8 KB
    __shared__ __align__(16) _Float16 ldsX[2][8 * 32 * 8];    // 8 KB

    const float* Ug[4] = {Ui, Uf, Uh, Uo};
    const float* Vg[4] = {Vi, Vf, Vh, Vo};
    const float* bg[4] = {bi, bf, bh, bo};

    // ---- one-time fragment preload (fp32 -> fp16 cvt) ----
    h8 vfrag[4][16];   // V: K=512 -> 16 k-chunks
    h8 ufrag[4][8];    // U: K=256 ->  8 k-chunks
    float bias[4];
#pragma unroll
    for (int g = 0; g < 4; ++g) {
        bias[g] = bg[g][unit];
#pragma unroll
        for (int kc = 0; kc < 16; ++kc) {
            h8 v;
#pragma unroll
            for (int jj = 0; jj < 8; ++jj)
                v[jj] = (_Float16)Vg[g][(size_t)(kc * 32 + hi * 8 + jj) * 512 + unit];
            vfrag[g][kc] = v;
        }
#pragma unroll
        for (int kc = 0; kc < 8; ++kc) {
            h8 u;
#pragma unroll
            for (int jj = 0; jj < 8; ++jj)
                u[jj] = (_Float16)Ug[g][(size_t)(kc * 32 + hi * 8 + jj) * 512 + unit];
            ufrag[g][kc] = u;
        }
    }

    // ---- staging map: thread -> (row sr, 8-unit granule at sc) per half ----
    const int sr = tid >> 5;              // batch row 0..7
    const int sc = (tid & 31) * 8;        // unit base within half (0..248)
    const int kc1 = sc >> 5;              // k-chunk 0..7 (half1); half2 = kc1+8
    const int hg1 = (sc >> 3) & 3;        // hi coord of granule
    const int sw1 = ((kc1 & 1) << 2) | hg1;        // swizzle (same for both halves)
    const int g1 = kc1 * 32 + hg1 * 8 + (sr ^ sw1);        // half1 / x granule
    const int g2 = (kc1 + 8) * 32 + hg1 * 8 + (sr ^ sw1);  // half2 granule

    const float* xrb = x + (size_t)(ig * 8 + sr) * 262144 + sc;

    f4 cst = {0.f, 0.f, 0.f, 0.f};
    f4 xq0, xq1;                          // prefetched x_{t+1}

    // ---- prologue: stage x_0 -> ldsX[0]; issue x_1 loads ----
    {
        f4 a0, a1;
        asm volatile("global_load_dwordx4 %0, %2, off\n\t"
                     "global_load_dwordx4 %1, %2, off offset:16"
                     : "=&v"(a0), "=&v"(a1) : "v"(xrb) : "memory");
        VWAIT0();
        *(h8*)&ldsX[0][(size_t)g1 * 8] = pack8f(a0, a1);
        const float* xp1 = xrb + 256;
        asm volatile("global_load_dwordx4 %0, %2, off\n\t"
                     "global_load_dwordx4 %1, %2, off offset:16"
                     : "=&v"(xq0), "=&v"(xq1) : "v"(xp1) : "memory");
        LBAR();
    }

    for (int t = 0; t < 1024; ++t) {
        const int pb = t & 1, pn = pb ^ 1;
        const int pr = (t + 1) & 1;                         // slab holding h_{t-1}
        const unsigned etag = (unsigned)((t + 1023) & 1023);
        const unsigned* hp = hbuf + (size_t)(pr * 8 + ig) * 4096
                                  + (size_t)sr * 512 + sc;

        // ---- issue all h probes (half1 then half2: youngest-2 == half2) ----
        u4 qa, qb, qc, qd;
        asm volatile(
            "global_load_dwordx4 %0, %4, off sc0 sc1\n\t"
            "global_load_dwordx4 %1, %4, off offset:16 sc0 sc1\n\t"
            "global_load_dwordx4 %2, %4, off offset:1024 sc0 sc1\n\t"
            "global_load_dwordx4 %3, %4, off offset:1040 sc0 sc1"
            : "=&v"(qa), "=&v"(qb), "=&v"(qc), "=&v"(qd)
            : "v"(hp) : "memory");

        // ---- phase A: gates = bias + x_t @ U (ldsX[pb], swizzled reads) ----
        f4 acc[4];
#pragma unroll
        for (int g = 0; g < 4; ++g) {
            f4 a; a[0] = bias[g]; a[1] = bias[g]; a[2] = bias[g]; a[3] = bias[g];
            acc[g] = a;
        }
#pragma unroll
        for (int kc = 0; kc < 8; ++kc) {
            const int ga = kc * 32 + hi * 8 + (r8 ^ (((kc & 1) << 2) | hi));
            const h8 xa = *(const h8*)&ldsX[pb][(size_t)ga * 8];
            acc[0] = __builtin_amdgcn_mfma_f32_16x16x32_f16(xa, ufrag[0][kc], acc[0], 0, 0, 0);
            acc[1] = __builtin_amdgcn_mfma_f32_16x16x32_f16(xa, ufrag[1][kc], acc[1], 0, 0, 0);
            acc[2] = __builtin_amdgcn_mfma_f32_16x16x32_f16(xa, ufrag[2][kc], acc[2], 0, 0, 0);
            acc[3] = __builtin_amdgcn_mfma_f32_16x16x32_f16(xa, ufrag[3][kc], acc[3], 0, 0, 0);
        }

        // ---- half-1 wait: vmcnt(2) retires pub stores, x loads, h1 ----
        VWAIT2();
        {
            int tries = 0;
            for (;;) {
                const unsigned m =
                    (qa[0]^etag)|(qa[1]^etag)|(qa[2]^etag)|(qa[3]^etag)|
                    (qb[0]^etag)|(qb[1]^etag)|(qb[2]^etag)|(qb[3]^etag);
                if (!(m & 1023u)) break;
                if (++tries > 8192) break;   // fails absmax, never hangs
                asm volatile(
                    "global_load_dwordx4 %0, %2, off sc0 sc1\n\t"
                    "global_load_dwordx4 %1, %2, off offset:16 sc0 sc1"
                    : "=&v"(qa), "=&v"(qb) : "v"(hp) : "memory");
                VWAIT0();
            }
        }
        // stage h1 (one b128, swizzled) + x_{t+1}
        *(h8*)&ldsH[(size_t)g1 * 8] = pack8h(qa, qb);
        *(h8*)&ldsX[pn][(size_t)g1 * 8] = pack8f(xq0, xq1);
        LBAR();

        // ---- phase Ba: h_{t-1} @ V, k-chunks 0..7 (h2 still in flight) ----
#pragma unroll
        for (int kc = 0; kc < 8; ++kc) {
            const int ga = kc * 32 + hi * 8 + (r8 ^ (((kc & 1) << 2) | hi));
            const h8 a = *(const h8*)&ldsH[(size_t)ga * 8];
            acc[0] = __builtin_amdgcn_mfma_f32_16x16x32_f16(a, vfrag[0][kc], acc[0], 0, 0, 0);
            acc[1] = __builtin_amdgcn_mfma_f32_16x16x32_f16(a, vfrag[1][kc], acc[1], 0, 0, 0);
            acc[2] = __builtin_amdgcn_mfma_f32_16x16x32_f16(a, vfrag[2][kc], acc[2], 0, 0, 0);
            acc[3] = __builtin_amdgcn_mfma_f32_16x16x32_f16(a, vfrag[3][kc], acc[3], 0, 0, 0);
        }

        // ---- half-2 wait ----
        VWAIT0();
        {
            int tries = 0;
            for (;;) {
                const unsigned m =
                    (qc[0]^etag)|(qc[1]^etag)|(qc[2]^etag)|(qc[3]^etag)|
                    (qd[0]^etag)|(qd[1]^etag)|(qd[2]^etag)|(qd[3]^etag);
                if (!(m & 1023u)) break;
                if (++tries > 8192) break;
                asm volatile(
                    "global_load_dwordx4 %0, %2, off offset:1024 sc0 sc1\n\t"
                    "global_load_dwordx4 %1, %2, off offset:1040 sc0 sc1"
                    : "=&v"(qc), "=&v"(qd) : "v"(hp) : "memory");
                VWAIT0();
            }
        }
        *(h8*)&ldsH[(size_t)g2 * 8] = pack8h(qc, qd);
        LBAR();

        // ---- phase Bb: h_{t-1} @ V, k-chunks 8..15 ----
#pragma unroll
        for (int kc = 8; kc < 16; ++kc) {
            const int ga = kc * 32 + hi * 8 + (r8 ^ (((kc & 1) << 2) | hi));
            const h8 a = *(const h8*)&ldsH[(size_t)ga * 8];
            acc[0] = __builtin_amdgcn_mfma_f32_16x16x32_f16(a, vfrag[0][kc], acc[0], 0, 0, 0);
            acc[1] = __builtin_amdgcn_mfma_f32_16x16x32_f16(a, vfrag[1][kc], acc[1], 0, 0, 0);
            acc[2] = __builtin_amdgcn_mfma_f32_16x16x32_f16(a, vfrag[2][kc], acc[2], 0, 0, 0);
            acc[3] = __builtin_amdgcn_mfma_f32_16x16x32_f16(a, vfrag[3][kc], acc[3], 0, 0, 0);
        }

        // ---- elementwise + tagged agent-scope publish (pinned asm) ----
        const unsigned ptag = (unsigned)(t & 1023);
        unsigned pub[4];
#pragma unroll
        for (int d = 0; d < 4; ++d) {
            const float iv = sigm(acc[0][d]);
            const float fv = sigm(acc[1][d]);
            const float gv = tanh_a(acc[2][d]);
            const float ov = sigm(acc[3][d]);
            const float c = fv * cst[d] + iv * gv;
            cst[d] = c;
            const float hv = ov * tanh_a(c);
            pub[d] = (__float_as_uint(hv) & 0xFFFFFC00u) | ptag;
        }
        if (hi < 2) {
            unsigned* hw = hbuf + (size_t)((pb * 8 + ig) * 8 + hi * 4) * 512 + unit;
            asm volatile(
                "global_store_dword %4, %0, off sc0 sc1\n\t"
                "global_store_dword %4, %1, off offset:2048 sc0 sc1\n\t"
                "global_store_dword %5, %2, off sc0 sc1\n\t"
                "global_store_dword %5, %3, off offset:2048 sc0 sc1"
                :: "v"(pub[0]), "v"(pub[1]), "v"(pub[2]), "v"(pub[3]),
                   "v"(hw), "v"(hw + 1024)
                : "memory");
        }

        // ---- issue x_{t+2} loads (older than next step's h probes) ----
        {
            const int tn = (t + 2 < 1024) ? t + 2 : 1023;
            const float* xp = xrb + (size_t)tn * 256;
            asm volatile("global_load_dwordx4 %0, %2, off\n\t"
                         "global_load_dwordx4 %1, %2, off offset:16"
                         : "=&v"(xq0), "=&v"(xq1) : "v"(xp) : "memory");
        }
    }
}

// ---------------- k_fc: out[b] = h_last[b,:] . fc_w + fc_b ----------------
__global__ __launch_bounds__(64) void k_fc(
    const unsigned* __restrict__ hbuf, const float* __restrict__ fcw,
    const float* __restrict__ fcb, float* __restrict__ out)
{
    const int b = blockIdx.x, l = threadIdx.x;
    // h_1023 lives at parity 1; ig = b>>3, row = b&7; mask the tag bits
    const unsigned* h = hbuf + (size_t)((8 + (b >> 3)) * 8 + (b & 7)) * 512;
    float s = 0.f;
#pragma unroll
    for (int k = 0; k < 8; ++k) {
        const float hv = __uint_as_float(h[l + k * 64] & 0xFFFFFC00u);
        s += hv * fcw[l + k * 64];
    }
    for (int off = 32; off > 0; off >>= 1) s += __shfl_down(s, off, 64);
    if (l == 0) out[b] = s + fcb[0];
}

__global__ __launch_bounds__(64) void k_sentinel(float* out)
{
    out[threadIdx.x] = -777777.0f;   // signature: ws_size too small
}

extern "C" void kernel_launch(void* const* d_in, const int* in_sizes, int n_in,
                              void* d_out, int out_size, void* d_ws, size_t ws_size,
                              hipStream_t stream)
{
    const float* x   = (const float*)d_in[0];
    const float* Ui  = (const float*)d_in[1];
    const float* Vi  = (const float*)d_in[2];
    const float* bi  = (const float*)d_in[3];
    const float* Uf  = (const float*)d_in[4];
    const float* Vf  = (const float*)d_in[5];
    const float* bf  = (const float*)d_in[6];
    const float* Uh  = (const float*)d_in[7];
    const float* Vh  = (const float*)d_in[8];
    const float* bh  = (const float*)d_in[9];
    const float* Uo  = (const float*)d_in[10];
    const float* Vo  = (const float*)d_in[11];
    const float* bo  = (const float*)d_in[12];
    const float* fcw = (const float*)d_in[13];
    const float* fcb = (const float*)d_in[14];
    float* out = (float*)d_out;

    if (ws_size < WS_NEEDED) {
        k_sentinel<<<1, 64, 0, stream>>>(out);
        return;
    }

    unsigned* hbuf = (unsigned*)d_ws;

    k_init<<<256, 256, 0, stream>>>(hbuf);
    k_rec <<<64,  256, 0, stream>>>(x, Ui, Vi, bi, Uf, Vf, bf, Uh, Vh, bh,
                                    Uo, Vo, bo, hbuf);
    k_fc  <<<64,   64, 0, stream>>>(hbuf, fcw, fcb, out);
}

// Round 4
// 2681.689 us; speedup vs baseline: 3.2359x; 1.2595x over previous
//
#include <hip/hip_runtime.h>

typedef _Float16 h8 __attribute__((ext_vector_type(8)));
typedef float    f4 __attribute__((ext_vector_type(4)));
typedef unsigned u4 __attribute__((ext_vector_type(4)));

// ---------------- workspace layout (bytes) ----------------
// hbuf32 : 2*8*8*512 fp32 = 262,144  [parity][ig 8][row 8][unit 512]
//          each dword: fp32 h with 10-bit step tag in mantissa LSBs
static const unsigned long long WS_NEEDED = 262144ull;

__device__ __forceinline__ float sigm(float x)   { return 1.0f / (1.0f + __expf(-x)); }
__device__ __forceinline__ float tanh_a(float x) { return 2.0f / (1.0f + __expf(-2.0f * x)) - 1.0f; }

// ---------------- k_init: fill h buffer with tag=1023, value~0 ----------------
__global__ __launch_bounds__(256) void k_init(unsigned* hbuf)
{
    const int idx = blockIdx.x * 256 + threadIdx.x;
    if (idx < 65536) hbuf[idx] = 0x000003FFu;
}

// R11 = R10 schedule with fixed wait discipline. R10's NaN: the ldsX[pn]
// write consumed xq0/xq1 (inline-asm loads from step t-1) with NO covering
// s_waitcnt on the zero-retry path (VWAIT2 deliberately left them in
// flight; the spin's VWAIT0 only ran on retries). Raw asm loads get no
// compiler-inserted waitcnt -> garbage stored to LDS.
// Fix: ONE unconditional VWAIT0 at the spin head. It retires prev-step
// publishes + the x-prefetch pair + the probes just issued. No counted
// vmcnt survives an iteration boundary; nothing else needs accounting.
// Schedule per step:
//   phase A (x@U, dual 4-deep MFMA chains)       <- also delays the probe
//   -> PROBE4 -> spin { VWAIT0; check; retry }   <- fresh sample, 1 RT
//   -> stage x_{t+1} + both h halves -> issue x_{t+2} -> ONE barrier
//   -> phase B (h@V, dual 8-deep chains) -> elementwise -> publish
// Every waitcnt is followed by sched_barrier(0) (rule 18).

#define VWAIT0() do { asm volatile("s_waitcnt vmcnt(0)" ::: "memory"); \
                      __builtin_amdgcn_sched_barrier(0); } while (0)
#define LBAR()   do { asm volatile("s_waitcnt lgkmcnt(0)" ::: "memory"); \
                      __builtin_amdgcn_s_barrier(); \
                      __builtin_amdgcn_sched_barrier(0); } while (0)

#define PROBE4() \
    asm volatile( \
        "global_load_dwordx4 %0, %4, off sc0 sc1\n\t" \
        "global_load_dwordx4 %1, %4, off offset:16 sc0 sc1\n\t" \
        "global_load_dwordx4 %2, %4, off offset:1024 sc0 sc1\n\t" \
        "global_load_dwordx4 %3, %4, off offset:1040 sc0 sc1" \
        : "=&v"(qa), "=&v"(qb), "=&v"(qc), "=&v"(qd) \
        : "v"(hp) : "memory")

__device__ __forceinline__ h8 pack8h(u4 a, u4 b)
{
    h8 p;
    p[0] = (_Float16)__uint_as_float(a[0] & 0xFFFFFC00u);
    p[1] = (_Float16)__uint_as_float(a[1] & 0xFFFFFC00u);
    p[2] = (_Float16)__uint_as_float(a[2] & 0xFFFFFC00u);
    p[3] = (_Float16)__uint_as_float(a[3] & 0xFFFFFC00u);
    p[4] = (_Float16)__uint_as_float(b[0] & 0xFFFFFC00u);
    p[5] = (_Float16)__uint_as_float(b[1] & 0xFFFFFC00u);
    p[6] = (_Float16)__uint_as_float(b[2] & 0xFFFFFC00u);
    p[7] = (_Float16)__uint_as_float(b[3] & 0xFFFFFC00u);
    return p;
}
__device__ __forceinline__ h8 pack8f(f4 a, f4 b)
{
    h8 p;
    p[0] = (_Float16)a[0]; p[1] = (_Float16)a[1];
    p[2] = (_Float16)a[2]; p[3] = (_Float16)a[3];
    p[4] = (_Float16)b[0]; p[5] = (_Float16)b[1];
    p[6] = (_Float16)b[2]; p[7] = (_Float16)b[3];
    return p;
}

__global__ __launch_bounds__(256, 1) void k_rec(
    const float* __restrict__ x,
    const float* __restrict__ Ui, const float* __restrict__ Vi, const float* __restrict__ bi,
    const float* __restrict__ Uf, const float* __restrict__ Vf, const float* __restrict__ bf,
    const float* __restrict__ Uh, const float* __restrict__ Vh, const float* __restrict__ bh,
    const float* __restrict__ Uo, const float* __restrict__ Vo, const float* __restrict__ bo,
    unsigned* hbuf)
{
    const int bx = blockIdx.x;
    const int ig = bx & 7;
    const int jg = bx >> 3;
    const int tid = threadIdx.x;
    const int w = tid >> 6, l = tid & 63;
    const int lo = l & 15, hi = l >> 4;
    const int r8 = lo & 7;
    const int unit = jg * 64 + w * 16 + lo;

    // double-buffered (parity = t&1): one barrier per step, race-free
    __shared__ __align__(16) _Float16 ldsH[2][16 * 32 * 8];   // 16 KB
    __shared__ __align__(16) _Float16 ldsX[2][8 * 32 * 8];    //  8 KB

    const float* Ug[4] = {Ui, Uf, Uh, Uo};
    const float* Vg[4] = {Vi, Vf, Vh, Vo};
    const float* bg[4] = {bi, bf, bh, bo};

    // ---- one-time fragment preload (fp32 -> fp16 cvt) ----
    h8 vfrag[4][16];   // V: K=512 -> 16 k-chunks
    h8 ufrag[4][8];    // U: K=256 ->  8 k-chunks
    float bias[4];
#pragma unroll
    for (int g = 0; g < 4; ++g) {
        bias[g] = bg[g][unit];
#pragma unroll
        for (int kc = 0; kc < 16; ++kc) {
            h8 v;
#pragma unroll
            for (int jj = 0; jj < 8; ++jj)
                v[jj] = (_Float16)Vg[g][(size_t)(kc * 32 + hi * 8 + jj) * 512 + unit];
            vfrag[g][kc] = v;
        }
#pragma unroll
        for (int kc = 0; kc < 8; ++kc) {
            h8 u;
#pragma unroll
            for (int jj = 0; jj < 8; ++jj)
                u[jj] = (_Float16)Ug[g][(size_t)(kc * 32 + hi * 8 + jj) * 512 + unit];
            ufrag[g][kc] = u;
        }
    }

    // ---- staging map: thread -> (row sr, 8-unit granule at sc) per half ----
    const int sr = tid >> 5;              // batch row 0..7
    const int sc = (tid & 31) * 8;        // unit base within half (0..248)
    const int kc1 = sc >> 5;              // k-chunk 0..7 (half1); half2 = kc1+8
    const int hg1 = (sc >> 3) & 3;        // hi coord of granule
    const int sw1 = ((kc1 & 1) << 2) | hg1;
    const int g1 = kc1 * 32 + hg1 * 8 + (sr ^ sw1);        // half1 / x granule
    const int g2 = (kc1 + 8) * 32 + hg1 * 8 + (sr ^ sw1);  // half2 granule

    const float* xrb = x + (size_t)(ig * 8 + sr) * 262144 + sc;

    f4 cst = {0.f, 0.f, 0.f, 0.f};
    f4 xq0, xq1;                          // prefetched x_{t+1}

    // ---- prologue: stage x_0 -> ldsX[0]; issue x_1 loads ----
    {
        f4 a0, a1;
        asm volatile("global_load_dwordx4 %0, %2, off\n\t"
                     "global_load_dwordx4 %1, %2, off offset:16"
                     : "=&v"(a0), "=&v"(a1) : "v"(xrb) : "memory");
        VWAIT0();
        *(h8*)&ldsX[0][(size_t)g1 * 8] = pack8f(a0, a1);
        const float* xp1 = xrb + 256;
        asm volatile("global_load_dwordx4 %0, %2, off\n\t"
                     "global_load_dwordx4 %1, %2, off offset:16"
                     : "=&v"(xq0), "=&v"(xq1) : "v"(xp1) : "memory");
        LBAR();
    }

    for (int t = 0; t < 1024; ++t) {
        const int pb = t & 1, pn = pb ^ 1;
        const int pr = (t + 1) & 1;                         // slab holding h_{t-1}
        const unsigned etag = (unsigned)((t + 1023) & 1023);
        const unsigned* hp = hbuf + (size_t)(pr * 8 + ig) * 4096
                                  + (size_t)sr * 512 + sc;

        // ---- phase A: gates = bias + x_t @ U; dual 4-deep chains.
        //      Runs BEFORE the probes so the probe samples MALL after the
        //      producers' end-of-step publishes are visible. ----
        f4 acc[4], acq[4];
#pragma unroll
        for (int g = 0; g < 4; ++g) {
            f4 a; a[0] = bias[g]; a[1] = bias[g]; a[2] = bias[g]; a[3] = bias[g];
            acc[g] = a;
            f4 z; z[0] = 0.f; z[1] = 0.f; z[2] = 0.f; z[3] = 0.f;
            acq[g] = z;
        }
#pragma unroll
        for (int k = 0; k < 4; ++k) {
            const int ke = 2 * k, ko = 2 * k + 1;
            const int ga = ke * 32 + hi * 8 + (r8 ^ (((ke & 1) << 2) | hi));
            const int gb = ko * 32 + hi * 8 + (r8 ^ (((ko & 1) << 2) | hi));
            const h8 xa = *(const h8*)&ldsX[pb][(size_t)ga * 8];
            const h8 xb = *(const h8*)&ldsX[pb][(size_t)gb * 8];
            acc[0] = __builtin_amdgcn_mfma_f32_16x16x32_f16(xa, ufrag[0][ke], acc[0], 0, 0, 0);
            acc[1] = __builtin_amdgcn_mfma_f32_16x16x32_f16(xa, ufrag[1][ke], acc[1], 0, 0, 0);
            acc[2] = __builtin_amdgcn_mfma_f32_16x16x32_f16(xa, ufrag[2][ke], acc[2], 0, 0, 0);
            acc[3] = __builtin_amdgcn_mfma_f32_16x16x32_f16(xa, ufrag[3][ke], acc[3], 0, 0, 0);
            acq[0] = __builtin_amdgcn_mfma_f32_16x16x32_f16(xb, ufrag[0][ko], acq[0], 0, 0, 0);
            acq[1] = __builtin_amdgcn_mfma_f32_16x16x32_f16(xb, ufrag[1][ko], acq[1], 0, 0, 0);
            acq[2] = __builtin_amdgcn_mfma_f32_16x16x32_f16(xb, ufrag[2][ko], acq[2], 0, 0, 0);
            acq[3] = __builtin_amdgcn_mfma_f32_16x16x32_f16(xb, ufrag[3][ko], acq[3], 0, 0, 0);
        }

        // ---- issue all 4 h probes (deliberately after phase A) ----
        u4 qa, qb, qc, qd;
        PROBE4();

        // ---- spin: unconditional VWAIT0 at head retires prev publishes,
        //      the x-prefetch pair (making xq0/xq1 safe), and the probes ----
        {
            int tries = 0;
            for (;;) {
                VWAIT0();
                const unsigned m =
                    (qa[0]^etag)|(qa[1]^etag)|(qa[2]^etag)|(qa[3]^etag)|
                    (qb[0]^etag)|(qb[1]^etag)|(qb[2]^etag)|(qb[3]^etag)|
                    (qc[0]^etag)|(qc[1]^etag)|(qc[2]^etag)|(qc[3]^etag)|
                    (qd[0]^etag)|(qd[1]^etag)|(qd[2]^etag)|(qd[3]^etag);
                if (__all((m & 1023u) == 0u)) break;
                if (++tries > 8192) break;   // fails absmax, never hangs
                PROBE4();
            }
        }

        // ---- stage x_{t+1} (xq now retired) + both h halves ----
        *(h8*)&ldsX[pn][(size_t)g1 * 8] = pack8f(xq0, xq1);
        *(h8*)&ldsH[pb][(size_t)g1 * 8] = pack8h(qa, qb);
        *(h8*)&ldsH[pb][(size_t)g2 * 8] = pack8h(qc, qd);

        // ---- issue x_{t+2} loads (retired by next step's spin VWAIT0) ----
        {
            const int tn = (t + 2 < 1024) ? t + 2 : 1023;
            const float* xp = xrb + (size_t)tn * 256;
            asm volatile("global_load_dwordx4 %0, %2, off\n\t"
                         "global_load_dwordx4 %1, %2, off offset:16"
                         : "=&v"(xq0), "=&v"(xq1) : "v"(xp) : "memory");
        }

        LBAR();   // the ONLY barrier per step

        // ---- phase B: h_{t-1} @ V; dual 8-deep chains (kc k and k+8) ----
#pragma unroll
        for (int k = 0; k < 8; ++k) {
            const int kh = k + 8;
            const int ga = k  * 32 + hi * 8 + (r8 ^ (((k  & 1) << 2) | hi));
            const int gb = kh * 32 + hi * 8 + (r8 ^ (((kh & 1) << 2) | hi));
            const h8 a0 = *(const h8*)&ldsH[pb][(size_t)ga * 8];
            const h8 a1 = *(const h8*)&ldsH[pb][(size_t)gb * 8];
            acc[0] = __builtin_amdgcn_mfma_f32_16x16x32_f16(a0, vfrag[0][k],  acc[0], 0, 0, 0);
            acc[1] = __builtin_amdgcn_mfma_f32_16x16x32_f16(a0, vfrag[1][k],  acc[1], 0, 0, 0);
            acc[2] = __builtin_amdgcn_mfma_f32_16x16x32_f16(a0, vfrag[2][k],  acc[2], 0, 0, 0);
            acc[3] = __builtin_amdgcn_mfma_f32_16x16x32_f16(a0, vfrag[3][k],  acc[3], 0, 0, 0);
            acq[0] = __builtin_amdgcn_mfma_f32_16x16x32_f16(a1, vfrag[0][kh], acq[0], 0, 0, 0);
            acq[1] = __builtin_amdgcn_mfma_f32_16x16x32_f16(a1, vfrag[1][kh], acq[1], 0, 0, 0);
            acq[2] = __builtin_amdgcn_mfma_f32_16x16x32_f16(a1, vfrag[2][kh], acq[2], 0, 0, 0);
            acq[3] = __builtin_amdgcn_mfma_f32_16x16x32_f16(a1, vfrag[3][kh], acq[3], 0, 0, 0);
        }

        // ---- merge chains + elementwise + tagged agent-scope publish ----
        const unsigned ptag = (unsigned)(t & 1023);
        unsigned pub[4];
#pragma unroll
        for (int d = 0; d < 4; ++d) {
            const float iv = sigm(acc[0][d] + acq[0][d]);
            const float fv = sigm(acc[1][d] + acq[1][d]);
            const float gv = tanh_a(acc[2][d] + acq[2][d]);
            const float ov = sigm(acc[3][d] + acq[3][d]);
            const float c = fv * cst[d] + iv * gv;
            cst[d] = c;
            const float hv = ov * tanh_a(c);
            pub[d] = (__float_as_uint(hv) & 0xFFFFFC00u) | ptag;
        }
        if (hi < 2) {
            unsigned* hw = hbuf + (size_t)((pb * 8 + ig) * 8 + hi * 4) * 512 + unit;
            asm volatile(
                "global_store_dword %4, %0, off sc0 sc1\n\t"
                "global_store_dword %4, %1, off offset:2048 sc0 sc1\n\t"
                "global_store_dword %5, %2, off sc0 sc1\n\t"
                "global_store_dword %5, %3, off offset:2048 sc0 sc1"
                :: "v"(pub[0]), "v"(pub[1]), "v"(pub[2]), "v"(pub[3]),
                   "v"(hw), "v"(hw + 1024)
                : "memory");
        }
    }
}

// ---------------- k_fc: out[b] = h_last[b,:] . fc_w + fc_b ----------------
__global__ __launch_bounds__(64) void k_fc(
    const unsigned* __restrict__ hbuf, const float* __restrict__ fcw,
    const float* __restrict__ fcb, float* __restrict__ out)
{
    const int b = blockIdx.x, l = threadIdx.x;
    // h_1023 lives at parity 1; ig = b>>3, row = b&7; mask the tag bits
    const unsigned* h = hbuf + (size_t)((8 + (b >> 3)) * 8 + (b & 7)) * 512;
    float s = 0.f;
#pragma unroll
    for (int k = 0; k < 8; ++k) {
        const float hv = __uint_as_float(h[l + k * 64] & 0xFFFFFC00u);
        s += hv * fcw[l + k * 64];
    }
    for (int off = 32; off > 0; off >>= 1) s += __shfl_down(s, off, 64);
    if (l == 0) out[b] = s + fcb[0];
}

__global__ __launch_bounds__(64) void k_sentinel(float* out)
{
    out[threadIdx.x] = -777777.0f;   // signature: ws_size too small
}

extern "C" void kernel_launch(void* const* d_in, const int* in_sizes, int n_in,
                              void* d_out, int out_size, void* d_ws, size_t ws_size,
                              hipStream_t stream)
{
    const float* x   = (const float*)d_in[0];
    const float* Ui  = (const float*)d_in[1];
    const float* Vi  = (const float*)d_in[2];
    const float* bi  = (const float*)d_in[3];
    const float* Uf  = (const float*)d_in[4];
    const float* Vf  = (const float*)d_in[5];
    const float* bf  = (const float*)d_in[6];
    const float* Uh  = (const float*)d_in[7];
    const float* Vh  = (const float*)d_in[8];
    const float* bh  = (const float*)d_in[9];
    const float* Uo  = (const float*)d_in[10];
    const float* Vo  = (const float*)d_in[11];
    const float* bo  = (const float*)d_in[12];
    const float* fcw = (const float*)d_in[13];
    const float* fcb = (const float*)d_in[14];
    float* out = (float*)d_out;

    if (ws_size < WS_NEEDED) {
        k_sentinel<<<1, 64, 0, stream>>>(out);
        return;
    }

    unsigned* hbuf = (unsigned*)d_ws;

    k_init<<<256, 256, 0, stream>>>(hbuf);
    k_rec <<<64,  256, 0, stream>>>(x, Ui, Vi, bi, Uf, Vf, bf, Uh, Vh, bh,
                                    Uo, Vo, bo, hbuf);
    k_fc  <<<64,   64, 0, stream>>>(hbuf, fcw, fcb, out);
}